// Round 1
// 496.906 us; speedup vs baseline: 1.0326x; 1.0326x over previous
//
#include <hip/hip_runtime.h>

// T=512, B=512, K=8, V=5, H=30, NL=4, NLAB=3
#define TT 512
#define BB 512
#define KK 8
#define HH 30
#define GG 120   // 4*H
#define NLAYER 4

__device__ __forceinline__ float rcp_f(float x) { return __builtin_amdgcn_rcpf(x); }
__device__ __forceinline__ float rdlane_f(float v, int l) {
    return __int_as_float(__builtin_amdgcn_readlane(__float_as_int(v), l));
}
// packed f32 FMA, all-VGPR operands (broadcast operand comes from uniform LDS read)
__device__ __forceinline__ float2 pk_fma_v(float2 a, float2 b, float2 c) {
    float2 d;
    asm("v_pk_fma_f32 %0, %1, %2, %3" : "=v"(d) : "v"(a), "v"(b), "v"(c));
    return d;
}
// packed f32 FMA, broadcast operand in SGPR pair (attention epilogue only)
__device__ __forceinline__ float2 pk_fma_s(float2 a, float2 bs, float2 c) {
    float2 d;
    asm("v_pk_fma_f32 %0, %1, %2, %3" : "=v"(d) : "v"(a), "s"(bs), "v"(c));
    return d;
}
__device__ __forceinline__ float2 pk_add(float2 a, float2 b) {
    float2 d;
    asm("v_pk_add_f32 %0, %1, %2" : "=v"(d) : "v"(a), "v"(b));
    return d;
}
// value from lane^32 partner (valid for lanes < 32; lanes >= 32 get own/lo value)
__device__ __forceinline__ float swap32_hi(float x) {
    float a = x, b = x;
    asm("v_permlane32_swap_b32 %0, %1" : "+v"(a), "+v"(b));
    return b;   // lanes<32: x[lane+32]
}

// One block = one sample; 4 waves = 4 LSTM layers in an ELASTIC pipeline.
// R4: broadcasts (h and x) now come from uniform-address ds_read_b64 instead of
// 60 v_readlane/step; gate i/f and g/o exchange via v_permlane32_swap (XOR-32
// lane layout: lanes 0..29 own i,g rows; lanes 32..61 own f,o rows);
// amdgpu_waves_per_eu(2,2) raises the arch-VGPR budget to 256 so the 120-VGPR
// weight set stays register-resident (R3 kernel reported 108 VGPRs -> weights
// were AGPR-parked, forcing v_accvgpr_read copies at every pk_fma use).
__global__ __launch_bounds__(256) __attribute__((amdgpu_waves_per_eu(2, 2)))
void rnn_fused(
    const int*   __restrict__ xin,  const float* __restrict__ wxin,
    const float* __restrict__ embed,
    const float* __restrict__ Wih,  const float* __restrict__ Whh,
    const float* __restrict__ bih,  const float* __restrict__ bhh,
    const float* __restrict__ W1,   const float* __restrict__ b1,
    const float* __restrict__ W2,   const float* __restrict__ b2,
    const float* __restrict__ fcW,  const float* __restrict__ fcb,
    float* __restrict__ out)
{
    __shared__ alignas(16) float hstore[TT * HH];        // layer-3 h trace
    __shared__ alignas(16) float seqring[2][16][32];     // pooled-embed (wave-0 private)
    __shared__ alignas(16) int   ringx[4][16][KK];       // x stream (wave-0 private)
    __shared__ alignas(16) float ringw[4][16][KK];
    __shared__ alignas(16) float hring[NLAYER][8][32];   // per-layer h ring (self + next)
    __shared__ alignas(16) float re_s[5 * HH];           // relu(embed)
    __shared__ alignas(16) float energy_s[TT];
    __shared__ float red_s[16];
    __shared__ float part_s[8][HH];
    __shared__ float pooled_s[HH];
    __shared__ float logits_s[3];
    __shared__ int   sync_s[8];                          // [0..3]=prog, [4..7]=cons

    const int tid  = threadIdx.x;
    const int wv   = tid >> 6;
    const int lane = tid & 63;
    const int b    = blockIdx.x;
    volatile int* vs = sync_s;

    // ---- preamble ----
    if (tid < 8) sync_s[tid] = 0;
    if (tid < 5 * HH) re_s[tid] = fmaxf(embed[tid], 0.0f);
    {   // zero hring: t=0 self-reads slot 7 expect h=0 (1024 floats = 256 float4)
        float4 z; z.x = 0.f; z.y = 0.f; z.z = 0.f; z.w = 0.f;
        ((float4*)hring)[tid] = z;
    }

    int4 hx = {0,0,0,0}; float4 hw = {0,0,0,0};          // held x/w (wave0, lanes<32)
    if (wv == 0 && lane < 32) {
        const int r = lane >> 1, hf = lane & 1;
        #pragma unroll
        for (int cc = 0; cc < 2; ++cc) {                 // chunks 0,1 -> LDS
            long off = ((long)(16 * cc + r) * BB + b) * KK + hf * 4;
            *(int4*)(&ringx[cc][r][hf * 4])   = *(const int4*)(xin  + off);
            *(float4*)(&ringw[cc][r][hf * 4]) = *(const float4*)(wxin + off);
        }
        long off2 = ((long)(32 + r) * BB + b) * KK + hf * 4;  // chunk 2 -> regs
        hx = *(const int4*)(xin  + off2);
        hw = *(const float4*)(wxin + off2);
    }

    // ---- per-lane LSTM weights, XOR-32 gate layout ----
    // half0 (lanes 0..31, rows q + 0):   rowA = i-row q,   rowB = g-row q+60
    // half1 (lanes 32..63, rows q + 30): rowA = f-row q+30, rowB = o-row q+90
    const int half = lane >> 5;
    const int q31  = lane & 31;
    const int qq   = (q31 < HH) ? q31 : (HH - 1);        // clamp dead lanes
    const int rA   = qq + half * HH;                     // 0..59
    const int rB   = rA + 60;                            // 60..119
    float2 wihA[15], wihB[15], whhA[15], whhB[15];
    {
        const float* WihL = Wih + wv * GG * HH;
        const float* WhhL = Whh + wv * GG * HH;
        #pragma unroll
        for (int kk = 0; kk < 15; ++kk) {
            wihA[kk] = *(const float2*)(WihL + rA * HH + 2 * kk);
            wihB[kk] = *(const float2*)(WihL + rB * HH + 2 * kk);
            whhA[kk] = *(const float2*)(WhhL + rA * HH + 2 * kk);
            whhB[kk] = *(const float2*)(WhhL + rB * HH + 2 * kk);
        }
    }
    const float biasA = bih[wv * GG + rA] + bhh[wv * GG + rA];
    const float biasB = bih[wv * GG + rB] + bhh[wv * GG + rB];
    const float mBneg = (lane < 32) ? -2.0f : -1.0f;     // half0: tanh via 2*sig(2x)-1
    const float aB    = (lane < 32) ?  2.0f :  1.0f;
    const float dB    = (lane < 32) ? -1.0f :  0.0f;

    __syncthreads();   // preamble visible (ringx/re_s/hring-zero/sync init)

    float c_val = 0.0f;

    auto do_step = [&](int t) {
        // wave-uniform base pointers: ds_read_b64 at uniform addr = free broadcast
        const float* xsrc = (wv == 0) ? &seqring[(t >> 4) & 1][t & 15][0]
                                      : &hring[wv - 1][t & 7][0];
        const float* hsrc = &hring[wv][(t + 7) & 7][0];  // own h from step t-1
        float2 ah0 = {0.f,0.f}, ah1 = {0.f,0.f};
        float2 ax0 = {0.f,0.f}, ax1 = {0.f,0.f};
        #pragma unroll
        for (int k = 0; k < 15; ++k) {
            const float2 xp = *(const float2*)(xsrc + 2 * k);
            const float2 hp = *(const float2*)(hsrc + 2 * k);
            ax0 = pk_fma_v(wihA[k], xp, ax0);
            ax1 = pk_fma_v(wihB[k], xp, ax1);
            ah0 = pk_fma_v(whhA[k], hp, ah0);
            ah1 = pk_fma_v(whhB[k], hp, ah1);
        }
        const float2 s0 = pk_add(ax0, ah0);
        const float2 s1 = pk_add(ax1, ah1);
        const float gA = s0.x + s0.y + biasA;            // i | f
        const float gB = s1.x + s1.y + biasB;            // g | o
        const float actA = rcp_f(1.0f + __expf(-gA));    // sigmoid (both halves)
        const float sB   = rcp_f(1.0f + __expf(gB * mBneg));
        const float actB = fmaf(aB, sB, dB);             // tanh | sigmoid
        const float fI = swap32_hi(actA);                // f from lane+32
        const float oI = swap32_hi(actB);                // o from lane+32
        c_val = fmaf(fI, c_val, actA * actB);            // valid on lanes 0..29
        const float tC = fmaf(2.0f, rcp_f(1.0f + __expf(-2.0f * c_val)), -1.0f);
        const float hv = oI * tC;
        if (lane < HH) {
            hring[wv][t & 7][lane] = hv;                 // self (t+1) + next layer
            if (wv == NLAYER - 1) hstore[t * HH + lane] = hv;
        }
    };

    // ---- elastic pipelined recurrence: 128 groups of 4 steps ----
    for (int T0 = 0; T0 < TT; T0 += 4) {
        if (wv == 0) {
            if ((T0 & 15) == 0) {                        // chunk boundary (private)
                const int c = T0 >> 4;
                if (lane < 32) {
                    const int r = lane >> 1, hf = lane & 1;
                    if (c <= 29) {                       // commit chunk c+2
                        const int sl = (c + 2) & 3;
                        *(int4*)(&ringx[sl][r][hf * 4])   = hx;
                        *(float4*)(&ringw[sl][r][hf * 4]) = hw;
                    }
                    if (c <= 28) {                       // load chunk c+3
                        long off = ((long)(16 * (c + 3) + r) * BB + b) * KK + hf * 4;
                        hx = *(const int4*)(xin  + off);
                        hw = *(const float4*)(wxin + off);
                    }
                }
                const int sl = c & 3, par = c & 1;       // gather pooled chunk c
                #pragma unroll
                for (int rr = 0; rr < 8; ++rr) {
                    const int o = lane + rr * 64;
                    if (o < 480) {
                        const int tr = o / HH, j = o - tr * HH;
                        int4   xa = *(const int4*)(&ringx[sl][tr][0]);
                        int4   xb = *(const int4*)(&ringx[sl][tr][4]);
                        float4 wa = *(const float4*)(&ringw[sl][tr][0]);
                        float4 wb = *(const float4*)(&ringw[sl][tr][4]);
                        float acc = re_s[xa.x * HH + j] * wa.x;
                        acc = fmaf(re_s[xa.y * HH + j], wa.y, acc);
                        acc = fmaf(re_s[xa.z * HH + j], wa.z, acc);
                        acc = fmaf(re_s[xa.w * HH + j], wa.w, acc);
                        acc = fmaf(re_s[xb.x * HH + j], wb.x, acc);
                        acc = fmaf(re_s[xb.y * HH + j], wb.y, acc);
                        acc = fmaf(re_s[xb.z * HH + j], wb.z, acc);
                        acc = fmaf(re_s[xb.w * HH + j], wb.w, acc);
                        seqring[par][tr][j] = acc * 0.125f;
                    }
                }
                __threadfence_block();                   // gather visible to own reads
            }
        } else {
            while (vs[wv - 1] < T0 + 4) __builtin_amdgcn_s_sleep(2);   // x ready
        }
        if (wv < NLAYER - 1) {
            while (vs[4 + wv + 1] < T0 - 4) __builtin_amdgcn_s_sleep(2); // ring free
        }
        __threadfence_block();                           // order spins vs ring reads
        do_step(T0 + 0);
        do_step(T0 + 1);
        do_step(T0 + 2);
        do_step(T0 + 3);
        __threadfence_block();                           // drain h writes
        if (lane == 0) {
            if (wv < NLAYER - 1) vs[wv]     = T0 + 4;    // producer progress
            if (wv > 0)          vs[4 + wv] = T0 + 4;    // consumer progress
        }
    }

    __syncthreads();   // hstore complete

    // ---- attention, t-per-lane: e_t = relu(h_t @ W1 + b1) @ W2 + b2 ----
    {
        float w1cx[15], w1cy[15];                        // W1 column `lane`
        #pragma unroll
        for (int k = 0; k < 15; ++k) {
            w1cx[k] = W1[(2 * k) * 64 + lane];
            w1cy[k] = W1[(2 * k + 1) * 64 + lane];
        }
        const float b1v = b1[lane];
        const float w2v = W2[lane];
        const float b2v = b2[0];
        #pragma unroll
        for (int pass = 0; pass < 2; ++pass) {
            const int t = wv * 128 + pass * 64 + lane;   // each lane owns one t
            float2 h2[15];
            #pragma unroll
            for (int k = 0; k < 15; ++k)
                h2[k] = *(const float2*)(hstore + t * HH + 2 * k);
            float e = b2v;
            for (int u = 0; u < 64; ++u) {               // W1 broadcast via readlane
                float2 acc = {0.f, 0.f};
                #pragma unroll
                for (int k = 0; k < 15; ++k) {
                    float2 wp;
                    wp.x = rdlane_f(w1cx[k], u);
                    wp.y = rdlane_f(w1cy[k], u);
                    acc = pk_fma_s(h2[k], wp, acc);
                }
                const float su = acc.x + acc.y + rdlane_f(b1v, u);
                e = fmaf(fmaxf(su, 0.0f), rdlane_f(w2v, u), e);
            }
            energy_s[t] = e;
        }
    }
    __syncthreads();

    // ---- softmax over T ----
    float mx = -3.0e38f;
    for (int i = tid; i < TT; i += 256) mx = fmaxf(mx, energy_s[i]);
    #pragma unroll
    for (int m = 1; m < 64; m <<= 1) mx = fmaxf(mx, __shfl_xor(mx, m, 64));
    if (lane == 0) red_s[wv] = mx;
    __syncthreads();
    mx = fmaxf(fmaxf(red_s[0], red_s[1]), fmaxf(red_s[2], red_s[3]));
    float ssum = 0.0f;
    for (int i = tid; i < TT; i += 256) {
        float ev = __expf(energy_s[i] - mx);
        energy_s[i] = ev;
        ssum += ev;
    }
    #pragma unroll
    for (int m = 1; m < 64; m <<= 1) ssum += __shfl_xor(ssum, m, 64);
    if (lane == 0) red_s[8 + wv] = ssum;
    __syncthreads();
    const float invS = rcp_f(red_s[8] + red_s[9] + red_s[10] + red_s[11]);

    // ---- pooled_j = sum_t softmax_t * h[t][j] ----
    {
        const int g = tid >> 5, jj = tid & 31;
        if (jj < HH) {
            float part = 0.0f;
            for (int t = g; t < TT; t += 8)
                part = fmaf(energy_s[t] * invS, hstore[t * HH + jj], part);
            part_s[g][jj] = part;
        }
    }
    __syncthreads();
    if (tid < HH) {
        float pv = 0.0f;
        #pragma unroll
        for (int q = 0; q < 8; ++q) pv += part_s[q][tid];
        pooled_s[tid] = pv;
    }
    __syncthreads();

    // ---- FC (30->3) + softmax ----
    if (tid < 3) {
        float acc = fcb[tid];
        #pragma unroll
        for (int k = 0; k < HH; ++k) acc = fmaf(pooled_s[k], fcW[k * 3 + tid], acc);
        logits_s[tid] = acc;
    }
    __syncthreads();
    if (tid == 0) {
        float l0 = logits_s[0], l1 = logits_s[1], l2 = logits_s[2];
        float m3 = fmaxf(l0, fmaxf(l1, l2));
        float e0 = __expf(l0 - m3), e1 = __expf(l1 - m3), e2 = __expf(l2 - m3);
        float inv = rcp_f(e0 + e1 + e2);
        out[b * 3 + 0] = e0 * inv; out[b * 3 + 1] = e1 * inv; out[b * 3 + 2] = e2 * inv;
    }
}

extern "C" void kernel_launch(void* const* d_in, const int* in_sizes, int n_in,
                              void* d_out, int out_size, void* d_ws, size_t ws_size,
                              hipStream_t stream)
{
    (void)in_sizes; (void)n_in; (void)d_ws; (void)ws_size; (void)out_size;
    rnn_fused<<<BB, 256, 0, stream>>>(
        (const int*)  d_in[0],  (const float*)d_in[1],  (const float*)d_in[2],
        (const float*)d_in[3],  (const float*)d_in[4],  (const float*)d_in[5],
        (const float*)d_in[6],  (const float*)d_in[7],  (const float*)d_in[8],
        (const float*)d_in[9],  (const float*)d_in[10], (const float*)d_in[11],
        (const float*)d_in[12], (float*)d_out);
}